// Round 2
// baseline (20051.494 us; speedup 1.0000x reference)
//
#include <hip/hip_runtime.h>
#include <stdint.h>

#define Bz 64
#define Tz 512
#define Ez 512
#define Hz 512
#define G4 2048
#define Lz 12
#define START_ID 10
#define END_ID 11
#define TC 64              // T chunk
#define NCH 8              // number of chunks

typedef unsigned int uint32;
typedef unsigned short ushort16;

__device__ __forceinline__ float bf2f(uint32 u) {
    return __uint_as_float(u << 16);
}
__device__ __forceinline__ ushort16 f2bf(float f) {
    uint32 x = __float_as_uint(f);
    x += 0x7FFFu + ((x >> 16) & 1u);
    return (ushort16)(x >> 16);
}
__device__ __forceinline__ float sigf(float x) {
    return 1.0f / (1.0f + __expf(-x));
}
__device__ __forceinline__ float tanh_fast(float x) {
    return 1.0f - 2.0f / (__expf(2.0f * x) + 1.0f);
}

// ---------------- K0: w_hh -> transposed bf16 [2][K=512][G=2048] ----------------
__global__ __launch_bounds__(256) void wt_kernel(const float* __restrict__ w_hh_f,
                                                 const float* __restrict__ w_hh_r,
                                                 ushort16* __restrict__ w_t) {
    int idx = blockIdx.x * 256 + threadIdx.x;   // 0 .. 2*512*2048-1
    int d = idx >> 20;
    int rem = idx & 1048575;
    int k = rem >> 11;
    int g = rem & 2047;
    const float* w = d ? w_hh_r : w_hh_f;
    w_t[idx] = f2bf(w[g * Hz + k]);
}

// ---- K1 (per chunk): xgc[d][b*TC+tloc][g] = emb[sents[b, off_d+tloc]] @ W^T + b ----
__global__ __launch_bounds__(256) void xg_kernel(const int* __restrict__ sents,
                                                 const float* __restrict__ embedding,
                                                 const float* __restrict__ w_ih_f,
                                                 const float* __restrict__ b_f,
                                                 const float* __restrict__ w_ih_r,
                                                 const float* __restrict__ b_r,
                                                 ushort16* __restrict__ xgc,
                                                 int off_f, int off_r) {
    const int mT = blockIdx.x;       // 32 tiles of 128 rows (rows = Bz*TC = 4096)
    const int nT = blockIdx.y;       // 16 tiles of 128 cols
    const int d  = blockIdx.z;       // direction
    const float* W    = d ? w_ih_r : w_ih_f;
    const float* bias = d ? b_r : b_f;
    const int off     = d ? off_r : off_f;

    __shared__ float At[16][128];
    __shared__ float Bt[16][128];
    __shared__ int ids[128];

    const int tid = threadIdx.x;
    if (tid < 128) {
        int rlocal = mT * 128 + tid;           // b*TC + tloc
        int b = rlocal >> 6;
        int tloc = rlocal & (TC - 1);
        ids[tid] = sents[b * Tz + off + tloc];
    }
    __syncthreads();

    const int r  = tid >> 1;          // 0..127 staging row
    const int c8 = (tid & 1) * 8;     // 0 or 8

    const int ty = tid >> 4;          // 0..15
    const int tx = tid & 15;          // 0..15

    float acc[8][8];
    #pragma unroll
    for (int u = 0; u < 8; u++)
        #pragma unroll
        for (int v = 0; v < 8; v++) acc[u][v] = 0.0f;

    for (int k0 = 0; k0 < Ez; k0 += 16) {
        const float* arow = &embedding[(size_t)ids[r] * Ez + k0 + c8];
        float4 a0 = *(const float4*)(arow);
        float4 a1 = *(const float4*)(arow + 4);
        const float* brow = &W[(size_t)(nT * 128 + r) * Ez + k0 + c8];
        float4 b0 = *(const float4*)(brow);
        float4 b1 = *(const float4*)(brow + 4);
        __syncthreads();
        At[c8 + 0][r] = a0.x; At[c8 + 1][r] = a0.y; At[c8 + 2][r] = a0.z; At[c8 + 3][r] = a0.w;
        At[c8 + 4][r] = a1.x; At[c8 + 5][r] = a1.y; At[c8 + 6][r] = a1.z; At[c8 + 7][r] = a1.w;
        Bt[c8 + 0][r] = b0.x; Bt[c8 + 1][r] = b0.y; Bt[c8 + 2][r] = b0.z; Bt[c8 + 3][r] = b0.w;
        Bt[c8 + 4][r] = b1.x; Bt[c8 + 5][r] = b1.y; Bt[c8 + 6][r] = b1.z; Bt[c8 + 7][r] = b1.w;
        __syncthreads();
        #pragma unroll
        for (int kk = 0; kk < 16; kk++) {
            float4 av0 = *(const float4*)&At[kk][ty * 8];
            float4 av1 = *(const float4*)&At[kk][ty * 8 + 4];
            float4 bv0 = *(const float4*)&Bt[kk][tx * 8];
            float4 bv1 = *(const float4*)&Bt[kk][tx * 8 + 4];
            float af[8] = {av0.x, av0.y, av0.z, av0.w, av1.x, av1.y, av1.z, av1.w};
            float bf[8] = {bv0.x, bv0.y, bv0.z, bv0.w, bv1.x, bv1.y, bv1.z, bv1.w};
            #pragma unroll
            for (int u = 0; u < 8; u++)
                #pragma unroll
                for (int v = 0; v < 8; v++) acc[u][v] += af[u] * bf[v];
        }
    }

    ushort16* xgd = xgc + (size_t)d * ((size_t)Bz * TC * G4);
    const int m0 = mT * 128 + ty * 8;
    const int n0 = nT * 128 + tx * 8;
    #pragma unroll
    for (int u = 0; u < 8; u++) {
        #pragma unroll
        for (int v = 0; v < 8; v += 2) {
            float f0 = acc[u][v]     + bias[n0 + v];
            float f1 = acc[u][v + 1] + bias[n0 + v + 1];
            uint32 pack = (uint32)f2bf(f0) | ((uint32)f2bf(f1) << 16);
            *(uint32*)&xgd[(size_t)(m0 + u) * G4 + n0 + v] = pack;
        }
    }
}

// ---------------- K2 (per chunk): 64 LSTM steps, one block per (batch, dir) ----------------
__global__ __launch_bounds__(256) void lstm_kernel(const ushort16* __restrict__ xgc,
                                                   const ushort16* __restrict__ w_t,
                                                   ushort16* __restrict__ hs,
                                                   float* __restrict__ c_state,
                                                   int j) {
    const int d = blockIdx.x & 1;
    const int b = blockIdx.x >> 1;
    const int tid = threadIdx.x;       // owns hidden units 2*tid, 2*tid+1

    const ushort16* wtp = w_t + (size_t)d * ((size_t)Hz * G4) + 2 * tid;
    const ushort16* xgd = xgc + (size_t)d * ((size_t)Bz * TC * G4) + 2 * tid;
    ushort16* hsd       = hs + (size_t)d * ((size_t)Bz * Tz * Hz) + 2 * tid;
    float* cst          = c_state + ((size_t)d * Bz + b) * Hz + 2 * tid;

    __shared__ float h_lds[Hz];
    float h0 = 0.0f, h1 = 0.0f, c0 = 0.0f, c1 = 0.0f;
    if (j > 0) {
        int tprev = d ? (Tz - TC * j) : (TC * j - 1);
        uint32 hv = *(const uint32*)(hsd + ((size_t)b * Tz + tprev) * Hz);
        h0 = bf2f(hv & 0xFFFFu);
        h1 = bf2f(hv >> 16);
        c0 = cst[0];
        c1 = cst[1];
    }
    h_lds[2 * tid]     = h0;
    h_lds[2 * tid + 1] = h1;
    __syncthreads();

    for (int i = 0; i < TC; i++) {
        const int tloc = d ? (TC - 1 - i) : i;                    // position in chunk buffer
        const int t    = d ? (Tz - 1 - TC * j - i) : (TC * j + i); // global timestep
        const size_t xrow = (size_t)b * TC + tloc;
        const size_t hrow = (size_t)b * Tz + t;

        float pre0[4], pre1[4];
        #pragma unroll
        for (int q = 0; q < 4; q++) {
            uint32 xv = *(const uint32*)(xgd + xrow * G4 + q * 512);
            pre0[q] = bf2f(xv & 0xFFFFu);
            pre1[q] = bf2f(xv >> 16);
        }

        for (int k = 0; k < Hz; k += 4) {
            float4 h4 = *(const float4*)&h_lds[k];
            float hk[4] = {h4.x, h4.y, h4.z, h4.w};
            #pragma unroll
            for (int kk = 0; kk < 4; kk++) {
                const ushort16* wrow = wtp + (size_t)(k + kk) * G4;
                #pragma unroll
                for (int q = 0; q < 4; q++) {
                    uint32 w = *(const uint32*)(wrow + q * 512);
                    pre0[q] += hk[kk] * bf2f(w & 0xFFFFu);
                    pre1[q] += hk[kk] * bf2f(w >> 16);
                }
            }
        }

        float i0 = sigf(pre0[0]), f0g = sigf(pre0[1]), g0 = tanh_fast(pre0[2]), o0 = sigf(pre0[3]);
        c0 = f0g * c0 + i0 * g0;
        float hn0 = o0 * tanh_fast(c0);
        float i1 = sigf(pre1[0]), f1g = sigf(pre1[1]), g1 = tanh_fast(pre1[2]), o1 = sigf(pre1[3]);
        c1 = f1g * c1 + i1 * g1;
        float hn1 = o1 * tanh_fast(c1);

        __syncthreads();   // everyone done reading old h
        h_lds[2 * tid]     = hn0;
        h_lds[2 * tid + 1] = hn1;
        uint32 pack = (uint32)f2bf(hn0) | ((uint32)f2bf(hn1) << 16);
        *(uint32*)(hsd + hrow * Hz) = pack;
        __syncthreads();   // new h visible
    }

    cst[0] = c0;
    cst[1] = c1;
}

// ---------------- K3: feats = tanh(concat(hf,hr)) @ fc_w^T + fc_b ----------------
__global__ __launch_bounds__(256) void feat_kernel(const ushort16* __restrict__ hs,
                                                   const float* __restrict__ fc_w,
                                                   const float* __restrict__ fc_b,
                                                   float* __restrict__ feats) {
    const int m = blockIdx.x * 4 + (threadIdx.x >> 6);   // row (b*T+t)
    const int lane = threadIdx.x & 63;

    const ushort16* hf = hs + (size_t)m * Hz + lane * 8;
    const ushort16* hr = hs + (size_t)Bz * Tz * Hz + (size_t)m * Hz + lane * 8;
    uint4 vf = *(const uint4*)hf;
    uint4 vr = *(const uint4*)hr;

    float x[16];
    {
        uint32 w0 = vf.x, w1 = vf.y, w2 = vf.z, w3 = vf.w;
        x[0] = tanh_fast(bf2f(w0 & 0xFFFFu)); x[1] = tanh_fast(bf2f(w0 >> 16));
        x[2] = tanh_fast(bf2f(w1 & 0xFFFFu)); x[3] = tanh_fast(bf2f(w1 >> 16));
        x[4] = tanh_fast(bf2f(w2 & 0xFFFFu)); x[5] = tanh_fast(bf2f(w2 >> 16));
        x[6] = tanh_fast(bf2f(w3 & 0xFFFFu)); x[7] = tanh_fast(bf2f(w3 >> 16));
        w0 = vr.x; w1 = vr.y; w2 = vr.z; w3 = vr.w;
        x[8]  = tanh_fast(bf2f(w0 & 0xFFFFu)); x[9]  = tanh_fast(bf2f(w0 >> 16));
        x[10] = tanh_fast(bf2f(w1 & 0xFFFFu)); x[11] = tanh_fast(bf2f(w1 >> 16));
        x[12] = tanh_fast(bf2f(w2 & 0xFFFFu)); x[13] = tanh_fast(bf2f(w2 >> 16));
        x[14] = tanh_fast(bf2f(w3 & 0xFFFFu)); x[15] = tanh_fast(bf2f(w3 >> 16));
    }

    float out = 0.0f;
    #pragma unroll
    for (int l = 0; l < Lz; l++) {
        const float* wf = fc_w + (size_t)l * 1024 + lane * 8;
        const float* wr = wf + 512;
        float4 a0 = *(const float4*)wf;
        float4 a1 = *(const float4*)(wf + 4);
        float4 b0 = *(const float4*)wr;
        float4 b1 = *(const float4*)(wr + 4);
        float s = a0.x * x[0] + a0.y * x[1] + a0.z * x[2] + a0.w * x[3]
                + a1.x * x[4] + a1.y * x[5] + a1.z * x[6] + a1.w * x[7]
                + b0.x * x[8] + b0.y * x[9] + b0.z * x[10] + b0.w * x[11]
                + b1.x * x[12] + b1.y * x[13] + b1.z * x[14] + b1.w * x[15];
        #pragma unroll
        for (int off = 32; off; off >>= 1) s += __shfl_xor(s, off);
        if (lane == l) out = s + fc_b[l];
    }
    if (lane < Lz) feats[(size_t)m * Lz + lane] = out;
}

// ---------------- K4: CRF log_z + gold per batch ----------------
__global__ __launch_bounds__(64) void crf_kernel(const float* __restrict__ feats,
                                                 const float* __restrict__ trans,
                                                 const int* __restrict__ labels,
                                                 const int* __restrict__ lengths,
                                                 float* __restrict__ res) {
    const int b = blockIdx.x;
    const int lane = threadIdx.x;
    const int jj = (lane < Lz) ? lane : 0;

    float tcol[12];
    #pragma unroll
    for (int i = 0; i < 12; i++) tcol[i] = trans[i * Lz + jj];
    const int len = lengths[b];

    float alpha = 0.0f;
    for (int t = 0; t < Tz; t++) {
        float feat = feats[((size_t)b * Tz + t) * Lz + jj];
        float v[12];
        #pragma unroll
        for (int i = 0; i < 12; i++) v[i] = __shfl(alpha, i) + tcol[i];
        float m = v[0];
        #pragma unroll
        for (int i = 1; i < 12; i++) m = fmaxf(m, v[i]);
        float s = 0.0f;
        #pragma unroll
        for (int i = 0; i < 12; i++) s += __expf(v[i] - m);
        float newa = feat + m + __logf(s);
        if (t < len && lane < Lz) alpha = newa;
    }

    float val = (lane < Lz) ? (alpha + trans[jj * Lz + END_ID]) : -INFINITY;
    float m = val;
    #pragma unroll
    for (int off = 32; off; off >>= 1) m = fmaxf(m, __shfl_xor(m, off));
    float s = (lane < Lz) ? __expf(val - m) : 0.0f;
    #pragma unroll
    for (int off = 32; off; off >>= 1) s += __shfl_xor(s, off);
    float log_z = m + __logf(s);

    float g = 0.0f;
    for (int t = lane; t < Tz; t += 64) {
        if (t < len) {
            int nxt = labels[b * Tz + t];
            int prev = (t == 0) ? START_ID : labels[b * Tz + t - 1];
            g += feats[((size_t)b * Tz + t) * Lz + nxt] + trans[prev * Lz + nxt];
        }
    }
    #pragma unroll
    for (int off = 32; off; off >>= 1) g += __shfl_xor(g, off);
    int last = labels[b * Tz + len - 1];
    float gold = g + trans[last * Lz + END_ID];

    if (lane == 0) res[b] = log_z - gold;
}

// ---------------- K5: final reduce ----------------
__global__ __launch_bounds__(64) void reduce_kernel(const float* __restrict__ res,
                                                    float* __restrict__ out) {
    float v = res[threadIdx.x];
    #pragma unroll
    for (int off = 32; off; off >>= 1) v += __shfl_xor(v, off);
    if (threadIdx.x == 0) out[0] = v;
}

extern "C" void kernel_launch(void* const* d_in, const int* in_sizes, int n_in,
                              void* d_out, int out_size, void* d_ws, size_t ws_size,
                              hipStream_t stream) {
    const int*   sents     = (const int*)d_in[0];
    const int*   labels    = (const int*)d_in[1];
    const int*   lengths   = (const int*)d_in[2];
    const float* embedding = (const float*)d_in[3];
    const float* w_ih_f    = (const float*)d_in[4];
    const float* w_hh_f    = (const float*)d_in[5];
    const float* b_f       = (const float*)d_in[6];
    const float* w_ih_r    = (const float*)d_in[7];
    const float* w_hh_r    = (const float*)d_in[8];
    const float* b_r       = (const float*)d_in[9];
    const float* fc_w      = (const float*)d_in[10];
    const float* fc_b      = (const float*)d_in[11];
    const float* trans     = (const float*)d_in[12];
    (void)in_sizes; (void)n_in; (void)out_size; (void)ws_size;

    // Workspace layout (~102 MB total):
    char* ws = (char*)d_ws;
    size_t off = 0;
    ushort16* xgc   = (ushort16*)(ws + off); off += (size_t)2 * Bz * TC * G4 * 2;   // 33,554,432
    ushort16* hs    = (ushort16*)(ws + off); off += (size_t)2 * Bz * Tz * Hz * 2;   // 67,108,864
    ushort16* w_t   = (ushort16*)(ws + off); off += (size_t)2 * Hz * G4 * 2;        //  4,194,304
    float*    feats = (float*)(ws + off);    off += (size_t)Bz * Tz * Lz * 4;       //  1,572,864
    float*    c_st  = (float*)(ws + off);    off += (size_t)2 * Bz * Hz * 4;        //    262,144
    float*    res   = (float*)(ws + off);    off += Bz * 4;                         //        256

    wt_kernel<<<8192, 256, 0, stream>>>(w_hh_f, w_hh_r, w_t);

    dim3 g1(32, 16, 2);   // 4096 rows / 128, 2048 cols / 128, 2 dirs
    for (int j = 0; j < NCH; j++) {
        int off_f = TC * j;
        int off_r = Tz - TC - TC * j;
        xg_kernel<<<g1, 256, 0, stream>>>(sents, embedding, w_ih_f, b_f, w_ih_r, b_r,
                                          xgc, off_f, off_r);
        lstm_kernel<<<128, 256, 0, stream>>>(xgc, w_t, hs, c_st, j);
    }

    feat_kernel<<<8192, 256, 0, stream>>>(hs, fc_w, fc_b, feats);
    crf_kernel<<<64, 64, 0, stream>>>(feats, trans, labels, lengths, res);
    reduce_kernel<<<1, 64, 0, stream>>>(res, (float*)d_out);
}

// Round 3
// 9412.808 us; speedup vs baseline: 2.1302x; 2.1302x over previous
//
#include <hip/hip_runtime.h>
#include <stdint.h>

#define Bz 64
#define Tz 512
#define Ez 512
#define Hz 512
#define Lz 12
#define START_ID 10
#define END_ID 11

typedef unsigned int uint32;
typedef unsigned short ushort16;
typedef __bf16 bf16x8 __attribute__((ext_vector_type(8)));
typedef float f32x4 __attribute__((ext_vector_type(4)));

__device__ __forceinline__ float bf2f(uint32 u) {
    return __uint_as_float(u << 16);
}
__device__ __forceinline__ ushort16 f2bf(float f) {
    uint32 x = __float_as_uint(f);
    x += 0x7FFFu + ((x >> 16) & 1u);
    return (ushort16)(x >> 16);
}
__device__ __forceinline__ float sigf(float x) {
    return 1.0f / (1.0f + __expf(-x));
}
__device__ __forceinline__ float tanh_fast(float x) {
    return 1.0f - 2.0f / (__expf(2.0f * x) + 1.0f);
}
__device__ __forceinline__ bf16x8 packbf8(float4 a, float4 b) {
    union { ushort16 u[8]; bf16x8 v; } r;
    r.u[0] = f2bf(a.x); r.u[1] = f2bf(a.y); r.u[2] = f2bf(a.z); r.u[3] = f2bf(a.w);
    r.u[4] = f2bf(b.x); r.u[5] = f2bf(b.y); r.u[6] = f2bf(b.z); r.u[7] = f2bf(b.w);
    return r.v;
}

// ---- K0: pack embeds into A-fragment order: emb_p[((bg*512+t)*16+kst)*64 + lane] = 16B ----
// lane l supplies A[row = bg*16 + (l&15)][k = kst*32 + (l>>4)*8 + i], i=0..7
__global__ __launch_bounds__(256) void prepack_kernel(const int* __restrict__ sents,
                                                      const float* __restrict__ emb,
                                                      uint4* __restrict__ emb_p) {
    int c = blockIdx.x * 256 + threadIdx.x;      // 0 .. 2^21-1
    int l   = c & 63;
    int kst = (c >> 6) & 15;
    int t   = (c >> 10) & 511;
    int bg  = c >> 19;
    int b   = (bg << 4) + (l & 15);
    int e0  = (kst << 5) + ((l >> 4) << 3);
    const float* p = emb + (size_t)sents[b * Tz + t] * Ez + e0;
    float4 f0 = *(const float4*)p;
    float4 f1 = *(const float4*)(p + 4);
    uint32 r0 = (uint32)f2bf(f0.x) | ((uint32)f2bf(f0.y) << 16);
    uint32 r1 = (uint32)f2bf(f0.z) | ((uint32)f2bf(f0.w) << 16);
    uint32 r2 = (uint32)f2bf(f1.x) | ((uint32)f2bf(f1.y) << 16);
    uint32 r3 = (uint32)f2bf(f1.z) | ((uint32)f2bf(f1.w) << 16);
    emb_p[c] = make_uint4(r0, r1, r2, r3);
}

// ---- K1: persistent BiLSTM. 256 blocks = 2 dir x 4 bgroup(16 batch) x 32 ugroup(16 units).
// Wave w (0..3) = gate type w. W_ih/W_hh B-fragments live in registers (128 VGPR).
// Per step: x-GEMM (MFMA, packed embeds) -> group spin-barrier -> h fill (swizzled LDS)
// -> h-GEMM (MFMA) -> gate exchange -> activation/c-update -> h_new to ping-pong + hs.
__global__ __launch_bounds__(256, 1) void lstm_persist(
    const float* __restrict__ w_ih_f, const float* __restrict__ w_hh_f, const float* __restrict__ b_f,
    const float* __restrict__ w_ih_r, const float* __restrict__ w_hh_r, const float* __restrict__ b_r,
    const uint4* __restrict__ emb_p,
    ushort16* __restrict__ hs,          // [2][64][512][512] bf16
    ushort16* __restrict__ h_pp,        // [2 parity][2 dir][64][512] bf16
    uint32* __restrict__ bar)           // 8 groups x 32-uint stride
{
    const int bid = blockIdx.x;
    const int d   = bid & 1;
    const int bg  = (bid >> 1) & 3;
    const int ug  = bid >> 3;            // 0..31
    const int tid = threadIdx.x;
    const int w   = tid >> 6;            // wave = gate type
    const int l   = tid & 63;
    const int grp = (d << 2) + bg;

    __shared__ __align__(16) char h_lds[16384];      // [16 b][512 k] bf16, XOR-swizzled
    __shared__ float gx[1024];                       // [16 b][4 gate][16 u] f32
    __shared__ ushort16 h_stage[256];                // [16 b][16 u] bf16

    const float* Whh  = d ? w_hh_r : w_hh_f;
    const float* Wih  = d ? w_ih_r : w_ih_f;
    const float* bias = d ? b_r : b_f;
    const int u0 = ug << 4;

    // ---- load B-fragments into registers ----
    // B[k][n]: lane l holds col n = l&15 (unit), k = kst*32 + (l>>4)*8 + i
    const int wrow = (w << 9) + u0 + (l & 15);       // row of W (gate*512 + unit)
    const int koff = (l >> 4) << 3;
    bf16x8 Bih[16], Bhh[16];
    #pragma unroll
    for (int kst = 0; kst < 16; kst++) {
        const float* p = Wih + (size_t)wrow * Ez + (kst << 5) + koff;
        Bih[kst] = packbf8(*(const float4*)p, *(const float4*)(p + 4));
        const float* q = Whh + (size_t)wrow * Hz + (kst << 5) + koff;
        Bhh[kst] = packbf8(*(const float4*)q, *(const float4*)(q + 4));
    }

    // activation-phase constants: thread = (b = tid>>4, u = tid&15)
    const int au = tid & 15;
    const float bi  = bias[u0 + au];
    const float bff = bias[512 + u0 + au];
    const float bgg = bias[1024 + u0 + au];
    const float bo  = bias[1536 + u0 + au];
    float c = 0.0f;

    // zero h(-1)
    for (int i = tid; i < 4096; i += 256) ((float*)h_lds)[i] = 0.0f;
    __syncthreads();

    const int r16 = tid >> 4, seg = tid & 15;
    uint32* barg = bar + (grp << 5);
    const uint4* h_pp4 = (const uint4*)h_pp;

    for (int t = 0; t < Tz; t++) {
        const int tg = d ? (Tz - 1 - t) : t;

        f32x4 acc[4];
        #pragma unroll
        for (int i = 0; i < 4; i++) acc[i] = (f32x4){0.f, 0.f, 0.f, 0.f};

        // ---- x-GEMM (independent of h -> overlaps barrier wait of other blocks) ----
        const uint4* xb = emb_p + ((((size_t)bg << 9) + tg) << 10) + l;
        #pragma unroll
        for (int kst = 0; kst < 16; kst++) {
            union { uint4 q; bf16x8 v; } x;
            x.q = xb[(size_t)kst << 6];
            acc[kst & 3] = __builtin_amdgcn_mfma_f32_16x16x32_bf16(x.v, Bih[kst], acc[kst & 3], 0, 0, 0);
        }

        // ---- wait for h(t-1); fill swizzled h LDS ----
        if (t > 0) {
            if (tid == 0) {
                const uint32 tgt = (uint32)t << 5;   // 32 blocks per group per step
                while (__hip_atomic_load(barg, __ATOMIC_RELAXED, __HIP_MEMORY_SCOPE_AGENT) < tgt)
                    __builtin_amdgcn_s_sleep(2);
            }
            __syncthreads();
            __builtin_amdgcn_fence(__ATOMIC_ACQUIRE, "agent");
            const uint4* rowp = h_pp4 + ((size_t)((((t - 1) & 1) << 1) + d) * 64 + (bg << 4) + r16) * 64;
            #pragma unroll
            for (int jj = 0; jj < 4; jj++) {
                uint4 v = rowp[(seg << 2) + jj];
                *(uint4*)(h_lds + (r16 << 10) + ((((seg << 2) + jj) << 4) ^ (r16 << 4))) = v;
            }
            __syncthreads();
        }

        // ---- h-GEMM ----
        #pragma unroll
        for (int kst = 0; kst < 16; kst++) {
            bf16x8 a = *(const bf16x8*)(h_lds + ((l & 15) << 10) +
                        (((kst << 6) + ((l >> 4) << 4)) ^ ((l & 15) << 4)));
            acc[kst & 3] = __builtin_amdgcn_mfma_f32_16x16x32_bf16(a, Bhh[kst], acc[kst & 3], 0, 0, 0);
        }

        f32x4 g4 = (acc[0] + acc[1]) + (acc[2] + acc[3]);

        // ---- gate exchange: D[row=(l>>4)*4+r][col=l&15] -> gx[b][gate][u] ----
        #pragma unroll
        for (int r = 0; r < 4; r++) {
            int b = ((l >> 4) << 2) + r;
            gx[(b << 6) + (w << 4) + (l & 15)] = g4[r];
        }
        __syncthreads();

        // ---- activation + c update (1 (b,u) pair per thread) ----
        {
            int b = tid >> 4;
            float gi = gx[(b << 6) + au];
            float gf = gx[(b << 6) + 16 + au];
            float gg = gx[(b << 6) + 32 + au];
            float go = gx[(b << 6) + 48 + au];
            c = sigf(gf + bff) * c + sigf(gi + bi) * tanh_fast(gg + bgg);
            float hn = sigf(go + bo) * tanh_fast(c);
            h_stage[tid] = f2bf(hn);
        }
        __syncthreads();

        // ---- wave0: publish h_new (ping-pong + hs output), release, arrive ----
        if (w == 0) {
            int br = l >> 2, sg = l & 3;
            uint2 v = *(const uint2*)((const ushort16*)h_stage + (br << 4) + (sg << 2));
            size_t prow = ((size_t)(((t & 1) << 1) + d) * 64 + (bg << 4) + br) * 512 + u0 + (sg << 2);
            *(uint2*)(h_pp + prow) = v;
            size_t hrow = (((size_t)(d << 6) + (bg << 4) + br) * 512 + tg) * 512 + u0 + (sg << 2);
            *(uint2*)(hs + hrow) = v;
            __builtin_amdgcn_fence(__ATOMIC_RELEASE, "agent");
        }
        if (tid == 0)
            __hip_atomic_fetch_add(barg, 1u, __ATOMIC_RELEASE, __HIP_MEMORY_SCOPE_AGENT);
    }
}

// ---------------- K3: feats = tanh(concat(hf,hr)) @ fc_w^T + fc_b ----------------
__global__ __launch_bounds__(256) void feat_kernel(const ushort16* __restrict__ hs,
                                                   const float* __restrict__ fc_w,
                                                   const float* __restrict__ fc_b,
                                                   float* __restrict__ feats) {
    const int m = blockIdx.x * 4 + (threadIdx.x >> 6);   // row (b*T+t)
    const int lane = threadIdx.x & 63;

    const ushort16* hf = hs + (size_t)m * Hz + lane * 8;
    const ushort16* hr = hs + (size_t)Bz * Tz * Hz + (size_t)m * Hz + lane * 8;
    uint4 vf = *(const uint4*)hf;
    uint4 vr = *(const uint4*)hr;

    float x[16];
    {
        uint32 w0 = vf.x, w1 = vf.y, w2 = vf.z, w3 = vf.w;
        x[0] = tanh_fast(bf2f(w0 & 0xFFFFu)); x[1] = tanh_fast(bf2f(w0 >> 16));
        x[2] = tanh_fast(bf2f(w1 & 0xFFFFu)); x[3] = tanh_fast(bf2f(w1 >> 16));
        x[4] = tanh_fast(bf2f(w2 & 0xFFFFu)); x[5] = tanh_fast(bf2f(w2 >> 16));
        x[6] = tanh_fast(bf2f(w3 & 0xFFFFu)); x[7] = tanh_fast(bf2f(w3 >> 16));
        w0 = vr.x; w1 = vr.y; w2 = vr.z; w3 = vr.w;
        x[8]  = tanh_fast(bf2f(w0 & 0xFFFFu)); x[9]  = tanh_fast(bf2f(w0 >> 16));
        x[10] = tanh_fast(bf2f(w1 & 0xFFFFu)); x[11] = tanh_fast(bf2f(w1 >> 16));
        x[12] = tanh_fast(bf2f(w2 & 0xFFFFu)); x[13] = tanh_fast(bf2f(w2 >> 16));
        x[14] = tanh_fast(bf2f(w3 & 0xFFFFu)); x[15] = tanh_fast(bf2f(w3 >> 16));
    }

    float out = 0.0f;
    #pragma unroll
    for (int ll = 0; ll < Lz; ll++) {
        const float* wf = fc_w + (size_t)ll * 1024 + lane * 8;
        const float* wr = wf + 512;
        float4 a0 = *(const float4*)wf;
        float4 a1 = *(const float4*)(wf + 4);
        float4 b0 = *(const float4*)wr;
        float4 b1 = *(const float4*)(wr + 4);
        float s = a0.x * x[0] + a0.y * x[1] + a0.z * x[2] + a0.w * x[3]
                + a1.x * x[4] + a1.y * x[5] + a1.z * x[6] + a1.w * x[7]
                + b0.x * x[8] + b0.y * x[9] + b0.z * x[10] + b0.w * x[11]
                + b1.x * x[12] + b1.y * x[13] + b1.z * x[14] + b1.w * x[15];
        #pragma unroll
        for (int off = 32; off; off >>= 1) s += __shfl_xor(s, off);
        if (lane == ll) out = s + fc_b[ll];
    }
    if (lane < Lz) feats[(size_t)m * Lz + lane] = out;
}

// ---------------- K4: CRF log_z + gold per batch ----------------
__global__ __launch_bounds__(64) void crf_kernel(const float* __restrict__ feats,
                                                 const float* __restrict__ trans,
                                                 const int* __restrict__ labels,
                                                 const int* __restrict__ lengths,
                                                 float* __restrict__ res) {
    const int b = blockIdx.x;
    const int lane = threadIdx.x;
    const int jj = (lane < Lz) ? lane : 0;

    float tcol[12];
    #pragma unroll
    for (int i = 0; i < 12; i++) tcol[i] = trans[i * Lz + jj];
    const int len = lengths[b];

    float alpha = 0.0f;
    for (int t = 0; t < Tz; t++) {
        float feat = feats[((size_t)b * Tz + t) * Lz + jj];
        float v[12];
        #pragma unroll
        for (int i = 0; i < 12; i++) v[i] = __shfl(alpha, i) + tcol[i];
        float m = v[0];
        #pragma unroll
        for (int i = 1; i < 12; i++) m = fmaxf(m, v[i]);
        float s = 0.0f;
        #pragma unroll
        for (int i = 0; i < 12; i++) s += __expf(v[i] - m);
        float newa = feat + m + __logf(s);
        if (t < len && lane < Lz) alpha = newa;
    }

    float val = (lane < Lz) ? (alpha + trans[jj * Lz + END_ID]) : -INFINITY;
    float m = val;
    #pragma unroll
    for (int off = 32; off; off >>= 1) m = fmaxf(m, __shfl_xor(m, off));
    float s = (lane < Lz) ? __expf(val - m) : 0.0f;
    #pragma unroll
    for (int off = 32; off; off >>= 1) s += __shfl_xor(s, off);
    float log_z = m + __logf(s);

    float g = 0.0f;
    for (int t = lane; t < Tz; t += 64) {
        if (t < len) {
            int nxt = labels[b * Tz + t];
            int prev = (t == 0) ? START_ID : labels[b * Tz + t - 1];
            g += feats[((size_t)b * Tz + t) * Lz + nxt] + trans[prev * Lz + nxt];
        }
    }
    #pragma unroll
    for (int off = 32; off; off >>= 1) g += __shfl_xor(g, off);
    int last = labels[b * Tz + len - 1];
    float gold = g + trans[last * Lz + END_ID];

    if (lane == 0) res[b] = log_z - gold;
}

// ---------------- K5: final reduce ----------------
__global__ __launch_bounds__(64) void reduce_kernel(const float* __restrict__ res,
                                                    float* __restrict__ out) {
    float v = res[threadIdx.x];
    #pragma unroll
    for (int off = 32; off; off >>= 1) v += __shfl_xor(v, off);
    if (threadIdx.x == 0) out[0] = v;
}

extern "C" void kernel_launch(void* const* d_in, const int* in_sizes, int n_in,
                              void* d_out, int out_size, void* d_ws, size_t ws_size,
                              hipStream_t stream) {
    const int*   sents     = (const int*)d_in[0];
    const int*   labels    = (const int*)d_in[1];
    const int*   lengths   = (const int*)d_in[2];
    const float* embedding = (const float*)d_in[3];
    const float* w_ih_f    = (const float*)d_in[4];
    const float* w_hh_f    = (const float*)d_in[5];
    const float* b_f       = (const float*)d_in[6];
    const float* w_ih_r    = (const float*)d_in[7];
    const float* w_hh_r    = (const float*)d_in[8];
    const float* b_r       = (const float*)d_in[9];
    const float* fc_w      = (const float*)d_in[10];
    const float* fc_b      = (const float*)d_in[11];
    const float* trans     = (const float*)d_in[12];
    (void)in_sizes; (void)n_in; (void)out_size; (void)ws_size;

    // Workspace (~102.5 MB)
    char* ws = (char*)d_ws;
    size_t off = 0;
    uint4*    emb_p = (uint4*)(ws + off);    off += (size_t)4 * 512 * 16 * 64 * 16;  // 33,554,432
    ushort16* hs    = (ushort16*)(ws + off); off += (size_t)2 * Bz * Tz * Hz * 2;    // 67,108,864
    float*    feats = (float*)(ws + off);    off += (size_t)Bz * Tz * Lz * 4;        //  1,572,864
    ushort16* h_pp  = (ushort16*)(ws + off); off += (size_t)2 * 2 * Bz * Hz * 2;     //    262,144
    uint32*   bar   = (uint32*)(ws + off);   off += 4096;
    float*    res   = (float*)(ws + off);    off += Bz * 4;

    hipMemsetAsync(bar, 0, 4096, stream);
    prepack_kernel<<<8192, 256, 0, stream>>>(sents, embedding, emb_p);
    lstm_persist<<<256, 256, 0, stream>>>(w_ih_f, w_hh_f, b_f, w_ih_r, w_hh_r, b_r,
                                          emb_p, hs, h_pp, bar);
    feat_kernel<<<8192, 256, 0, stream>>>(hs, fc_w, fc_b, feats);
    crf_kernel<<<64, 64, 0, stream>>>(feats, trans, labels, lengths, res);
    reduce_kernel<<<1, 64, 0, stream>>>(res, (float*)d_out);
}

// Round 4
// 2171.093 us; speedup vs baseline: 9.2357x; 4.3355x over previous
//
#include <hip/hip_runtime.h>
#include <stdint.h>

#define Bz 64
#define Tz 512
#define Ez 512
#define Hz 512
#define Lz 12
#define START_ID 10
#define END_ID 11

typedef unsigned int uint32;
typedef unsigned long long uint64;
typedef unsigned short ushort16;
typedef __bf16 bf16x8 __attribute__((ext_vector_type(8)));
typedef float f32x4 __attribute__((ext_vector_type(4)));

__device__ __forceinline__ float bf2f(uint32 u) {
    return __uint_as_float(u << 16);
}
__device__ __forceinline__ ushort16 f2bf(float f) {
    uint32 x = __float_as_uint(f);
    x += 0x7FFFu + ((x >> 16) & 1u);
    return (ushort16)(x >> 16);
}
__device__ __forceinline__ float sigf(float x) {
    return 1.0f / (1.0f + __expf(-x));
}
__device__ __forceinline__ float tanh_fast(float x) {
    return 1.0f - 2.0f / (__expf(2.0f * x) + 1.0f);
}
__device__ __forceinline__ bf16x8 packbf8(float4 a, float4 b) {
    union { ushort16 u[8]; bf16x8 v; } r;
    r.u[0] = f2bf(a.x); r.u[1] = f2bf(a.y); r.u[2] = f2bf(a.z); r.u[3] = f2bf(a.w);
    r.u[4] = f2bf(b.x); r.u[5] = f2bf(b.y); r.u[6] = f2bf(b.z); r.u[7] = f2bf(b.w);
    return r.v;
}

// ---- K0: pack embeds into A-fragment order: emb_p[((bg*512+t)*16+kst)*64 + lane] = 16B ----
// lane l supplies A[row = bg*16 + (l&15)][k = kst*32 + (l>>4)*8 + i], i=0..7
__global__ __launch_bounds__(256) void prepack_kernel(const int* __restrict__ sents,
                                                      const float* __restrict__ emb,
                                                      uint4* __restrict__ emb_p) {
    int c = blockIdx.x * 256 + threadIdx.x;      // 0 .. 2^21-1
    int l   = c & 63;
    int kst = (c >> 6) & 15;
    int t   = (c >> 10) & 511;
    int bg  = c >> 19;
    int b   = (bg << 4) + (l & 15);
    int e0  = (kst << 5) + ((l >> 4) << 3);
    const float* p = emb + (size_t)sents[b * Tz + t] * Ez + e0;
    float4 f0 = *(const float4*)p;
    float4 f1 = *(const float4*)(p + 4);
    uint32 r0 = (uint32)f2bf(f0.x) | ((uint32)f2bf(f0.y) << 16);
    uint32 r1 = (uint32)f2bf(f0.z) | ((uint32)f2bf(f0.w) << 16);
    uint32 r2 = (uint32)f2bf(f1.x) | ((uint32)f2bf(f1.y) << 16);
    uint32 r3 = (uint32)f2bf(f1.z) | ((uint32)f2bf(f1.w) << 16);
    emb_p[c] = make_uint4(r0, r1, r2, r3);
}

// ---- K1: persistent BiLSTM. 128 blocks = 8 groups (2 dir x 4 bgroup of 16 batch) x 16 ugroups(32 units).
// grp = bid & 7  -> all 16 blocks of a group on one XCD (round-robin dispatch heuristic).
// Wave w = gate w; 32 units/block: W_ih/W_hh B-frags in ~256 VGPRs.
// Sync per step: write-through atomic h stores -> s_waitcnt vmcnt(0) -> syncthreads ->
// private slot store (no contention) ; consumers poll 16 slots with 16 lanes. NO fences.
__global__ __launch_bounds__(256, 1) void lstm_persist(
    const float* __restrict__ w_ih_f, const float* __restrict__ w_hh_f, const float* __restrict__ b_f,
    const float* __restrict__ w_ih_r, const float* __restrict__ w_hh_r, const float* __restrict__ b_r,
    const uint4* __restrict__ emb_p,
    ushort16* __restrict__ hs,          // [2][64][512][512] bf16
    uint32* __restrict__ h_pp,          // [2 parity][2 dir][64][256 words] (2 units/word)
    uint32* __restrict__ bar)           // 128 slots x 32-uint stride (128 B apart)
{
    const int bid = blockIdx.x;
    const int grp = bid & 7;
    const int d   = grp >> 2;
    const int bg  = grp & 3;
    const int ug  = bid >> 3;            // 0..15
    const int tid = threadIdx.x;
    const int w   = tid >> 6;            // wave = gate type
    const int l   = tid & 63;

    __shared__ __align__(16) char h_lds[16384];      // [16 b][512 k] bf16, XOR-swizzled (16B granularity)
    __shared__ float gx[2048];                       // [16 b][4 gate][32 u] f32

    const float* Whh  = d ? w_hh_r : w_hh_f;
    const float* Wih  = d ? w_ih_r : w_ih_f;
    const float* bias = d ? b_r : b_f;
    const int u0 = ug << 5;

    // ---- load B-fragments into registers (two 16-col halves nn=0,1) ----
    bf16x8 Bih[2][16], Bhh[2][16];
    #pragma unroll
    for (int nn = 0; nn < 2; nn++) {
        const int wrow = (w << 9) + u0 + (nn << 4) + (l & 15);
        const int koff = (l >> 4) << 3;
        #pragma unroll
        for (int kst = 0; kst < 16; kst++) {
            const float* p = Wih + (size_t)wrow * Ez + (kst << 5) + koff;
            Bih[nn][kst] = packbf8(*(const float4*)p, *(const float4*)(p + 4));
            const float* q = Whh + (size_t)wrow * Hz + (kst << 5) + koff;
            Bhh[nn][kst] = packbf8(*(const float4*)q, *(const float4*)(q + 4));
        }
    }

    // activation thread mapping: b = tid>>4 (0..15 local), uw = tid&15 -> units 2*uw, 2*uw+1
    const int ab = tid >> 4;
    const int uw = tid & 15;
    const float bi0  = bias[u0 + 2*uw],        bi1  = bias[u0 + 2*uw + 1];
    const float bf0  = bias[512 + u0 + 2*uw],  bf1  = bias[512 + u0 + 2*uw + 1];
    const float bg0  = bias[1024 + u0 + 2*uw], bg1  = bias[1024 + u0 + 2*uw + 1];
    const float bo0  = bias[1536 + u0 + 2*uw], bo1  = bias[1536 + u0 + 2*uw + 1];
    float c0 = 0.0f, c1 = 0.0f;

    const int r16 = tid >> 4, seg = tid & 15;
    uint32* slot = bar + (((grp << 4) + ug) << 5);
    const uint64* h_pp64 = (const uint64*)h_pp;
    const uint4* xbase = emb_p + (((size_t)bg << 9) << 10);

    // preload x fragments for t=0
    uint4 xf[16];
    {
        const uint4* xb = xbase + ((size_t)(d ? (Tz - 1) : 0) << 10) + l;
        #pragma unroll
        for (int kst = 0; kst < 16; kst++) xf[kst] = xb[(size_t)kst << 6];
    }

    for (int t = 0; t < Tz; t++) {
        const int tg = d ? (Tz - 1 - t) : t;

        f32x4 acc[2][2];
        #pragma unroll
        for (int nn = 0; nn < 2; nn++)
            #pragma unroll
            for (int i = 0; i < 2; i++) acc[nn][i] = (f32x4){0.f, 0.f, 0.f, 0.f};

        // ---- x-GEMM from prefetched registers ----
        #pragma unroll
        for (int kst = 0; kst < 16; kst++) {
            union { uint4 q; bf16x8 v; } x;
            x.q = xf[kst];
            acc[0][kst & 1] = __builtin_amdgcn_mfma_f32_16x16x32_bf16(x.v, Bih[0][kst], acc[0][kst & 1], 0, 0, 0);
            acc[1][kst & 1] = __builtin_amdgcn_mfma_f32_16x16x32_bf16(x.v, Bih[1][kst], acc[1][kst & 1], 0, 0, 0);
        }

        if (t > 0) {
            // ---- poll 16 private slots with 16 lanes (wave 0 only) ----
            if (tid < 64) {
                const uint32 tgt = (uint32)t;
                uint32* sl = bar + (((grp << 4) + (l & 15)) << 5);
                for (;;) {
                    uint32 v = tgt;
                    if (l < 16) v = __hip_atomic_load(sl, __ATOMIC_RELAXED, __HIP_MEMORY_SCOPE_AGENT);
                    if (__all((int)(v >= tgt))) break;
                    __builtin_amdgcn_s_sleep(1);
                }
            }
            __syncthreads();

            // ---- load h(t-1) -> swizzled LDS (u64 bypassing loads) ----
            const uint64* hp = h_pp64 + ((size_t)((((t - 1) & 1) << 1) + d) * 64 + (bg << 4) + r16) * 128;
            #pragma unroll
            for (int jj = 0; jj < 8; jj++) {
                const int idx8 = (seg << 3) + jj;
                uint64 v = __hip_atomic_load(hp + idx8, __ATOMIC_RELAXED, __HIP_MEMORY_SCOPE_AGENT);
                *(uint64*)(h_lds + (r16 << 10) + ((((idx8 >> 1) << 4) ^ (r16 << 4))) + ((idx8 & 1) << 3)) = v;
            }
            __syncthreads();

            // ---- h-GEMM ----
            #pragma unroll
            for (int kst = 0; kst < 16; kst++) {
                bf16x8 a = *(const bf16x8*)(h_lds + ((l & 15) << 10) +
                            (((kst << 6) + ((l >> 4) << 4)) ^ ((l & 15) << 4)));
                acc[0][kst & 1] = __builtin_amdgcn_mfma_f32_16x16x32_bf16(a, Bhh[0][kst], acc[0][kst & 1], 0, 0, 0);
                acc[1][kst & 1] = __builtin_amdgcn_mfma_f32_16x16x32_bf16(a, Bhh[1][kst], acc[1][kst & 1], 0, 0, 0);
            }
        }

        f32x4 g0 = acc[0][0] + acc[0][1];
        f32x4 g1 = acc[1][0] + acc[1][1];

        // ---- gate exchange: D[row=(l>>4)*4+r][col=l&15] -> gx[b][gate][u] ----
        #pragma unroll
        for (int r = 0; r < 4; r++) {
            const int b = ((l >> 4) << 2) + r;
            gx[(b << 7) + (w << 5) + (l & 15)] = g0[r];
            gx[(b << 7) + (w << 5) + 16 + (l & 15)] = g1[r];
        }
        __syncthreads();

        // ---- activation + direct publish (2 units per thread) ----
        uint32 hval;
        {
            const int base = (ab << 7) + (uw << 1);
            float gi_0 = gx[base],      gi_1 = gx[base + 1];
            float gf_0 = gx[base + 32], gf_1 = gx[base + 33];
            float gg_0 = gx[base + 64], gg_1 = gx[base + 65];
            float go_0 = gx[base + 96], go_1 = gx[base + 97];
            c0 = sigf(gf_0 + bf0) * c0 + sigf(gi_0 + bi0) * tanh_fast(gg_0 + bg0);
            float hn0 = sigf(go_0 + bo0) * tanh_fast(c0);
            c1 = sigf(gf_1 + bf1) * c1 + sigf(gi_1 + bi1) * tanh_fast(gg_1 + bg1);
            float hn1 = sigf(go_1 + bo1) * tanh_fast(c1);
            hval = (uint32)f2bf(hn0) | ((uint32)f2bf(hn1) << 16);
            const size_t pidx = ((size_t)(((t & 1) << 1) + d) * 64 + (bg << 4) + ab) * 256 + (ug << 4) + uw;
            __hip_atomic_store(h_pp + pidx, hval, __ATOMIC_RELAXED, __HIP_MEMORY_SCOPE_AGENT);
        }
        asm volatile("s_waitcnt vmcnt(0)" ::: "memory");   // write-through stores globally visible
        __syncthreads();
        if (tid == 0)
            __hip_atomic_store(slot, (uint32)(t + 1), __ATOMIC_RELAXED, __HIP_MEMORY_SCOPE_AGENT);

        // ---- off critical path: hs output + x prefetch for t+1 ----
        {
            const size_t hrow = (((size_t)(d << 6) + (bg << 4) + ab) * 512 + tg) * 512 + u0 + (uw << 1);
            *(uint32*)(hs + hrow) = hval;
        }
        if (t < Tz - 1) {
            const int tg2 = d ? (Tz - 2 - t) : (t + 1);
            const uint4* xb = xbase + ((size_t)tg2 << 10) + l;
            #pragma unroll
            for (int kst = 0; kst < 16; kst++) xf[kst] = xb[(size_t)kst << 6];
        }
    }
}

// ---------------- K3: feats = tanh(concat(hf,hr)) @ fc_w^T + fc_b ----------------
__global__ __launch_bounds__(256) void feat_kernel(const ushort16* __restrict__ hs,
                                                   const float* __restrict__ fc_w,
                                                   const float* __restrict__ fc_b,
                                                   float* __restrict__ feats) {
    const int m = blockIdx.x * 4 + (threadIdx.x >> 6);   // row (b*T+t)
    const int lane = threadIdx.x & 63;

    const ushort16* hf = hs + (size_t)m * Hz + lane * 8;
    const ushort16* hr = hs + (size_t)Bz * Tz * Hz + (size_t)m * Hz + lane * 8;
    uint4 vf = *(const uint4*)hf;
    uint4 vr = *(const uint4*)hr;

    float x[16];
    {
        uint32 w0 = vf.x, w1 = vf.y, w2 = vf.z, w3 = vf.w;
        x[0] = tanh_fast(bf2f(w0 & 0xFFFFu)); x[1] = tanh_fast(bf2f(w0 >> 16));
        x[2] = tanh_fast(bf2f(w1 & 0xFFFFu)); x[3] = tanh_fast(bf2f(w1 >> 16));
        x[4] = tanh_fast(bf2f(w2 & 0xFFFFu)); x[5] = tanh_fast(bf2f(w2 >> 16));
        x[6] = tanh_fast(bf2f(w3 & 0xFFFFu)); x[7] = tanh_fast(bf2f(w3 >> 16));
        w0 = vr.x; w1 = vr.y; w2 = vr.z; w3 = vr.w;
        x[8]  = tanh_fast(bf2f(w0 & 0xFFFFu)); x[9]  = tanh_fast(bf2f(w0 >> 16));
        x[10] = tanh_fast(bf2f(w1 & 0xFFFFu)); x[11] = tanh_fast(bf2f(w1 >> 16));
        x[12] = tanh_fast(bf2f(w2 & 0xFFFFu)); x[13] = tanh_fast(bf2f(w2 >> 16));
        x[14] = tanh_fast(bf2f(w3 & 0xFFFFu)); x[15] = tanh_fast(bf2f(w3 >> 16));
    }

    float out = 0.0f;
    #pragma unroll
    for (int ll = 0; ll < Lz; ll++) {
        const float* wf = fc_w + (size_t)ll * 1024 + lane * 8;
        const float* wr = wf + 512;
        float4 a0 = *(const float4*)wf;
        float4 a1 = *(const float4*)(wf + 4);
        float4 b0 = *(const float4*)wr;
        float4 b1 = *(const float4*)(wr + 4);
        float s = a0.x * x[0] + a0.y * x[1] + a0.z * x[2] + a0.w * x[3]
                + a1.x * x[4] + a1.y * x[5] + a1.z * x[6] + a1.w * x[7]
                + b0.x * x[8] + b0.y * x[9] + b0.z * x[10] + b0.w * x[11]
                + b1.x * x[12] + b1.y * x[13] + b1.z * x[14] + b1.w * x[15];
        #pragma unroll
        for (int off = 32; off; off >>= 1) s += __shfl_xor(s, off);
        if (lane == ll) out = s + fc_b[ll];
    }
    if (lane < Lz) feats[(size_t)m * Lz + lane] = out;
}

// ---------------- K4: CRF log_z + gold per batch ----------------
__global__ __launch_bounds__(64) void crf_kernel(const float* __restrict__ feats,
                                                 const float* __restrict__ trans,
                                                 const int* __restrict__ labels,
                                                 const int* __restrict__ lengths,
                                                 float* __restrict__ res) {
    const int b = blockIdx.x;
    const int lane = threadIdx.x;
    const int jj = (lane < Lz) ? lane : 0;

    float tcol[12];
    #pragma unroll
    for (int i = 0; i < 12; i++) tcol[i] = trans[i * Lz + jj];
    const int len = lengths[b];

    float alpha = 0.0f;
    for (int t = 0; t < Tz; t++) {
        float feat = feats[((size_t)b * Tz + t) * Lz + jj];
        float v[12];
        #pragma unroll
        for (int i = 0; i < 12; i++) v[i] = __shfl(alpha, i) + tcol[i];
        float m = v[0];
        #pragma unroll
        for (int i = 1; i < 12; i++) m = fmaxf(m, v[i]);
        float s = 0.0f;
        #pragma unroll
        for (int i = 0; i < 12; i++) s += __expf(v[i] - m);
        float newa = feat + m + __logf(s);
        if (t < len && lane < Lz) alpha = newa;
    }

    float val = (lane < Lz) ? (alpha + trans[jj * Lz + END_ID]) : -INFINITY;
    float m = val;
    #pragma unroll
    for (int off = 32; off; off >>= 1) m = fmaxf(m, __shfl_xor(m, off));
    float s = (lane < Lz) ? __expf(val - m) : 0.0f;
    #pragma unroll
    for (int off = 32; off; off >>= 1) s += __shfl_xor(s, off);
    float log_z = m + __logf(s);

    float g = 0.0f;
    for (int t = lane; t < Tz; t += 64) {
        if (t < len) {
            int nxt = labels[b * Tz + t];
            int prev = (t == 0) ? START_ID : labels[b * Tz + t - 1];
            g += feats[((size_t)b * Tz + t) * Lz + nxt] + trans[prev * Lz + nxt];
        }
    }
    #pragma unroll
    for (int off = 32; off; off >>= 1) g += __shfl_xor(g, off);
    int last = labels[b * Tz + len - 1];
    float gold = g + trans[last * Lz + END_ID];

    if (lane == 0) res[b] = log_z - gold;
}

// ---------------- K5: final reduce ----------------
__global__ __launch_bounds__(64) void reduce_kernel(const float* __restrict__ res,
                                                    float* __restrict__ out) {
    float v = res[threadIdx.x];
    #pragma unroll
    for (int off = 32; off; off >>= 1) v += __shfl_xor(v, off);
    if (threadIdx.x == 0) out[0] = v;
}

extern "C" void kernel_launch(void* const* d_in, const int* in_sizes, int n_in,
                              void* d_out, int out_size, void* d_ws, size_t ws_size,
                              hipStream_t stream) {
    const int*   sents     = (const int*)d_in[0];
    const int*   labels    = (const int*)d_in[1];
    const int*   lengths   = (const int*)d_in[2];
    const float* embedding = (const float*)d_in[3];
    const float* w_ih_f    = (const float*)d_in[4];
    const float* w_hh_f    = (const float*)d_in[5];
    const float* b_f       = (const float*)d_in[6];
    const float* w_ih_r    = (const float*)d_in[7];
    const float* w_hh_r    = (const float*)d_in[8];
    const float* b_r       = (const float*)d_in[9];
    const float* fc_w      = (const float*)d_in[10];
    const float* fc_b      = (const float*)d_in[11];
    const float* trans     = (const float*)d_in[12];
    (void)in_sizes; (void)n_in; (void)out_size; (void)ws_size;

    // Workspace (~102.5 MB)
    char* ws = (char*)d_ws;
    size_t off = 0;
    uint4*    emb_p = (uint4*)(ws + off);    off += (size_t)4 * 512 * 16 * 64 * 16;  // 33,554,432
    ushort16* hs    = (ushort16*)(ws + off); off += (size_t)2 * Bz * Tz * Hz * 2;    // 67,108,864
    float*    feats = (float*)(ws + off);    off += (size_t)Bz * Tz * Lz * 4;        //  1,572,864
    uint32*   h_pp  = (uint32*)(ws + off);   off += (size_t)2 * 2 * Bz * 256 * 4;    //    262,144
    uint32*   bar   = (uint32*)(ws + off);   off += 16384;
    float*    res   = (float*)(ws + off);    off += Bz * 4;

    hipMemsetAsync(bar, 0, 16384, stream);
    prepack_kernel<<<8192, 256, 0, stream>>>(sents, embedding, emb_p);
    lstm_persist<<<128, 256, 0, stream>>>(w_ih_f, w_hh_f, b_f, w_ih_r, w_hh_r, b_r,
                                          emb_p, hs, h_pp, bar);
    feat_kernel<<<8192, 256, 0, stream>>>(hs, fc_w, fc_b, feats);
    crf_kernel<<<64, 64, 0, stream>>>(feats, trans, labels, lengths, res);
    reduce_kernel<<<1, 64, 0, stream>>>(res, (float*)d_out);
}